// Round 6
// baseline (29842.120 us; speedup 1.0000x reference)
//
#include <hip/hip_runtime.h>
#include <math.h>

#define BB   64      // batch
#define TT   512     // time steps
#define CIN  32
#define THF  32
#define HH   1024    // hidden
#define LL   128
#define INF  64      // CIN + THF
#define KD   1088    // INF + HH
#define SR   1092    // LDS row stride (floats): 16B-aligned; 1092%32=4 -> 2-way max (free)

// ================= persistent kernel =================
// 256 wgs (1/CU) x 512 threads. wg (bg 0..3, cg 0..63): batches bg*16..+15,
// cols cg*16..+15. W tile staged into LDS ONCE, lives across all 512 steps
// (R3/R4 lesson: registers spill — LDS is allocator-proof).
// Thread (q 0..7, bp 0..3, nl 0..15): 4 batches x 1 col x k-slice [q*136,+136).
// Per-bg barrier (64 wgs) = R4's proven fence/atomic sequence.
__global__ __launch_bounds__(512)
void rnn_persist2(const float* __restrict__ x, const float* __restrict__ tfeat,
                  const float* __restrict__ W, const float* __restrict__ bias,
                  float* __restrict__ hbuf,
                  unsigned* __restrict__ bar_cnt,   // [4]
                  unsigned* __restrict__ bar_gen)   // [4]
{
    __shared__ float s[16 * SR];       // [16 batches][inputs(64)|h(1024)]
    __shared__ float Wl[16 * SR];      // [16 cols][k]  (persistent)
    __shared__ float zr[8][16][18];    // [q][batch][col] partials (pad 18: 2-way max)

    const int tid = threadIdx.x;
    const int bid = blockIdx.x;
    const int bg  = bid >> 6;          // 0..3
    const int cg  = bid & 63;          // 0..63
    const int b0  = bg * 16;
    const int c0  = cg * 16;

    const int q   = tid >> 6;          // 0..7
    const int r   = tid & 63;
    const int bp  = r >> 4;            // 0..3
    const int nl  = r & 15;            // 0..15
    const int k0  = q * 136;

    // ---- one-time: stage W cols c0..c0+15 transposed into Wl[col][k] ----
    for (int i = tid; i < 4 * KD; i += 512) {
        int k = i >> 2, h4 = i & 3;
        float4 v = *reinterpret_cast<const float4*>(&W[(size_t)k * HH + c0 + h4 * 4]);
        Wl[(h4 * 4 + 0) * SR + k] = v.x;
        Wl[(h4 * 4 + 1) * SR + k] = v.y;
        Wl[(h4 * 4 + 2) * SR + k] = v.z;
        Wl[(h4 * 4 + 3) * SR + k] = v.w;
    }
    // reducer threads' bias (tid<256 handles (b=tid>>4, col=tid&15))
    const float bnr = bias[c0 + (tid & 15)];

    for (int t = 0; t < TT; ++t) {
        const float* hprev = hbuf + (size_t)(t & 1) * (BB * HH);
        float*       hnext = hbuf + (size_t)((t + 1) & 1) * (BB * HH);

        // ---- stage h: 16 x 1024 floats = 4096 float4, fully coalesced ----
        const float4* hp4 = reinterpret_cast<const float4*>(hprev) + (size_t)b0 * 256;
        #pragma unroll
        for (int j = 0; j < 8; ++j) {
            int f = tid + 512 * j;          // 0..4095
            int b = f >> 8, c = f & 255;
            float4 v = hp4[f];
            *reinterpret_cast<float4*>(&s[b * SR + INF + 4 * c]) = v;
        }
        // ---- stage step-t inputs: 16 x 64 floats ----
        if (tid < 256) {
            int b = tid >> 4, jf = tid & 15;
            float4 v;
            if (jf < 8)
                v = *reinterpret_cast<const float4*>(&x[((size_t)(b0 + b) * TT + t) * CIN + jf * 4]);
            else
                v = *reinterpret_cast<const float4*>(&tfeat[((size_t)(b0 + b) * TT + t) * THF + (jf - 8) * 4]);
            *reinterpret_cast<float4*>(&s[b * SR + jf * 4]) = v;
        }
        __syncthreads();

        // ---- compute: 4 batches x 1 col x 136 k, all LDS ----
        // w-reads: 16 uniq addrs/wave (broadcast x4), s-reads: 4 uniq (broadcast x16)
        const float* wrow = &Wl[nl * SR + k0];
        const float* s0p  = &s[(4 * bp + 0) * SR + k0];
        const float* s1p  = &s[(4 * bp + 1) * SR + k0];
        const float* s2p  = &s[(4 * bp + 2) * SR + k0];
        const float* s3p  = &s[(4 * bp + 3) * SR + k0];
        float a00 = 0.f, a01 = 0.f, a10 = 0.f, a11 = 0.f;
        float a20 = 0.f, a21 = 0.f, a30 = 0.f, a31 = 0.f;
        #pragma unroll 2
        for (int j = 0; j < 34; ++j) {
            float4 w  = *reinterpret_cast<const float4*>(wrow + 4 * j);
            float4 v0 = *reinterpret_cast<const float4*>(s0p + 4 * j);
            a00 = fmaf(w.x, v0.x, a00); a01 = fmaf(w.y, v0.y, a01);
            a00 = fmaf(w.z, v0.z, a00); a01 = fmaf(w.w, v0.w, a01);
            float4 v1 = *reinterpret_cast<const float4*>(s1p + 4 * j);
            a10 = fmaf(w.x, v1.x, a10); a11 = fmaf(w.y, v1.y, a11);
            a10 = fmaf(w.z, v1.z, a10); a11 = fmaf(w.w, v1.w, a11);
            float4 v2 = *reinterpret_cast<const float4*>(s2p + 4 * j);
            a20 = fmaf(w.x, v2.x, a20); a21 = fmaf(w.y, v2.y, a21);
            a20 = fmaf(w.z, v2.z, a20); a21 = fmaf(w.w, v2.w, a21);
            float4 v3 = *reinterpret_cast<const float4*>(s3p + 4 * j);
            a30 = fmaf(w.x, v3.x, a30); a31 = fmaf(w.y, v3.y, a31);
            a30 = fmaf(w.z, v3.z, a30); a31 = fmaf(w.w, v3.w, a31);
        }
        zr[q][4 * bp + 0][nl] = a00 + a01;
        zr[q][4 * bp + 1][nl] = a10 + a11;
        zr[q][4 * bp + 2][nl] = a20 + a21;
        zr[q][4 * bp + 3][nl] = a30 + a31;
        __syncthreads();

        // ---- reduce over q, tanh, coalesced h_next write ----
        if (tid < 256) {
            int b = tid >> 4, n2 = tid & 15;
            float z = bnr;
            #pragma unroll
            for (int g = 0; g < 8; ++g) z += zr[g][b][n2];
            hnext[(size_t)(b0 + b) * HH + c0 + n2] = tanhf(z);
        }

        // ---- per-bg barrier over 64 wgs (R4's proven sequence) ----
        __threadfence();
        __syncthreads();
        if (tid == 0) {
            const unsigned target = (unsigned)(t + 1);
            unsigned arrive = __hip_atomic_fetch_add(&bar_cnt[bg], 1u,
                                 __ATOMIC_ACQ_REL, __HIP_MEMORY_SCOPE_AGENT) + 1u;
            if (arrive == 64u * target) {
                __hip_atomic_store(&bar_gen[bg], target,
                                   __ATOMIC_RELEASE, __HIP_MEMORY_SCOPE_AGENT);
            } else {
                while (__hip_atomic_load(&bar_gen[bg],
                                         __ATOMIC_ACQUIRE, __HIP_MEMORY_SCOPE_AGENT) < target) {
                    __builtin_amdgcn_s_sleep(2);
                }
            }
        }
        __syncthreads();
    }
}

// ================= epilogue =================
__global__ __launch_bounds__(128)
void rnn_out(const float* __restrict__ h, const float* __restrict__ Wout,
             const float* __restrict__ bout, float* __restrict__ out)
{
    __shared__ float hl[HH];
    const int b = blockIdx.x, tid = threadIdx.x;
    for (int i = tid; i < HH / 4; i += 128)
        *reinterpret_cast<float4*>(hl + 4 * i) =
            *reinterpret_cast<const float4*>(h + (size_t)b * HH + 4 * i);
    __syncthreads();
    float a0 = bout[tid], a1 = 0.f, a2 = 0.f, a3 = 0.f;
    for (int j = 0; j < HH; j += 4) {
        a0 = fmaf(hl[j + 0], Wout[(size_t)(j + 0) * LL + tid], a0);
        a1 = fmaf(hl[j + 1], Wout[(size_t)(j + 1) * LL + tid], a1);
        a2 = fmaf(hl[j + 2], Wout[(size_t)(j + 2) * LL + tid], a2);
        a3 = fmaf(hl[j + 3], Wout[(size_t)(j + 3) * LL + tid], a3);
    }
    out[(size_t)b * LL + tid] = (a0 + a1) + (a2 + a3);
}

// ================= fallback: R5 proven multi-launch step =================
__global__ __launch_bounds__(512)
void rnn_step2(const float* __restrict__ x, const float* __restrict__ tfeat,
               const float* __restrict__ W, const float* __restrict__ bias,
               const float* __restrict__ hprev, float* __restrict__ hnext, int t)
{
    __shared__ float s[16 * SR];
    __shared__ float Wl[8 * SR];
    __shared__ float zr2[8][16][9];

    const int tid = threadIdx.x;
    const int bid = blockIdx.x;
    const int bg  = bid >> 6;
    const int cg  = bid & 63;
    const int b0  = bg * 16;
    const int c0  = cg * 16;
    const int q   = tid >> 6;
    const int b8  = (tid >> 3) & 7;
    const int nl  = tid & 7;
    const int k0  = q * 136;

    const float4* hp4 = reinterpret_cast<const float4*>(hprev);
    #pragma unroll
    for (int i = tid; i < 4096; i += 512) {
        int b = i >> 8, c = i & 255;
        float4 v = hp4[(size_t)(b0 + b) * 256 + c];
        *reinterpret_cast<float4*>(&s[b * SR + INF + 4 * c]) = v;
    }
    if (tid < 256) {
        int b = tid >> 4, jf = tid & 15;
        float4 v;
        if (jf < 8)
            v = *reinterpret_cast<const float4*>(&x[((size_t)(b0 + b) * TT + t) * CIN + jf * 4]);
        else
            v = *reinterpret_cast<const float4*>(&tfeat[((size_t)(b0 + b) * TT + t) * THF + (jf - 8) * 4]);
        *reinterpret_cast<float4*>(&s[b * SR + jf * 4]) = v;
    }

    #pragma unroll
    for (int pass = 0; pass < 2; ++pass) {
        for (int i = tid; i < 2 * KD; i += 512) {
            int k = i >> 1, h4 = i & 1;
            float4 v = *reinterpret_cast<const float4*>(&W[(size_t)k * HH + c0 + pass * 8 + h4 * 4]);
            Wl[(h4 * 4 + 0) * SR + k] = v.x;
            Wl[(h4 * 4 + 1) * SR + k] = v.y;
            Wl[(h4 * 4 + 2) * SR + k] = v.z;
            Wl[(h4 * 4 + 3) * SR + k] = v.w;
        }
        __syncthreads();

        const float* wrow = &Wl[nl * SR + k0];
        const float* sA   = &s[(2 * b8) * SR + k0];
        const float* sB   = &s[(2 * b8 + 1) * SR + k0];
        float a0 = 0.f, a1 = 0.f, b0a = 0.f, b1a = 0.f;
        #pragma unroll 4
        for (int j = 0; j < 34; ++j) {
            float4 w  = *reinterpret_cast<const float4*>(wrow + 4 * j);
            float4 va = *reinterpret_cast<const float4*>(sA + 4 * j);
            float4 vb = *reinterpret_cast<const float4*>(sB + 4 * j);
            a0  = fmaf(w.x, va.x, a0);  a1  = fmaf(w.y, va.y, a1);
            a0  = fmaf(w.z, va.z, a0);  a1  = fmaf(w.w, va.w, a1);
            b0a = fmaf(w.x, vb.x, b0a); b1a = fmaf(w.y, vb.y, b1a);
            b0a = fmaf(w.z, vb.z, b0a); b1a = fmaf(w.w, vb.w, b1a);
        }
        zr2[q][2 * b8][nl]     = a0 + a1;
        zr2[q][2 * b8 + 1][nl] = b0a + b1a;
        __syncthreads();

        if (tid < 128) {
            int b = tid >> 3, np = tid & 7;
            float z = bias[c0 + pass * 8 + np];
            #pragma unroll
            for (int g = 0; g < 8; ++g) z += zr2[g][b][np];
            hnext[(size_t)(b0 + b) * HH + c0 + pass * 8 + np] = tanhf(z);
        }
        __syncthreads();
    }
}

// ================= tiny-ws fallback (R1, proven) =================
__global__ __launch_bounds__(512)
void rnn_scan_kernel(const float* __restrict__ x, const float* __restrict__ tf,
                     const float* __restrict__ W, const float* __restrict__ bias,
                     const float* __restrict__ Wout, const float* __restrict__ bout,
                     float* __restrict__ out)
{
    __shared__ float s[KD];
    const int b_idx = blockIdx.x, tid = threadIdx.x;
    if (tid < CIN)      s[tid] = x[b_idx * TT * CIN + tid];
    else if (tid < INF) s[tid] = tf[b_idx * TT * THF + (tid - CIN)];
    for (int i = tid; i < HH; i += 512) s[INF + i] = 0.0f;
    __syncthreads();
    const int j0 = tid * 2;
    const float bias0 = bias[j0], bias1 = bias[j0 + 1];
    for (int t = 0; t < TT; ++t) {
        float z0 = bias0, z1 = bias1;
        #pragma unroll 8
        for (int k = 0; k < KD; ++k) {
            const float2 wv = *reinterpret_cast<const float2*>(&W[(size_t)k * HH + j0]);
            const float sv = s[k];
            z0 = fmaf(sv, wv.x, z0);
            z1 = fmaf(sv, wv.y, z1);
        }
        float nin = 0.0f;
        const int tn = t + 1;
        if (tn < TT) {
            if (tid < CIN)      nin = x[b_idx * TT * CIN + tn * CIN + tid];
            else if (tid < INF) nin = tf[b_idx * TT * THF + tn * THF + (tid - CIN)];
        }
        __syncthreads();
        s[INF + j0]     = tanhf(z0);
        s[INF + j0 + 1] = tanhf(z1);
        if (tid < INF && tn < TT) s[tid] = nin;
        __syncthreads();
    }
    for (int lll = tid; lll < LL; lll += 512) {
        float acc = bout[lll];
        for (int j = 0; j < HH; ++j) acc = fmaf(s[INF + j], Wout[(size_t)j * LL + lll], acc);
        out[(size_t)b_idx * LL + lll] = acc;
    }
}

extern "C" void kernel_launch(void* const* d_in, const int* in_sizes, int n_in,
                              void* d_out, int out_size, void* d_ws, size_t ws_size,
                              hipStream_t stream) {
    const float* x    = (const float*)d_in[0];   // [64, 512, 32]
    const float* tf   = (const float*)d_in[1];   // [64, 512, 32]
    const float* W    = (const float*)d_in[2];   // [1088, 1024]
    const float* brnn = (const float*)d_in[3];   // [1024]
    const float* Wout = (const float*)d_in[4];   // [1024, 128]
    const float* bout = (const float*)d_in[5];   // [128]
    float* out = (float*)d_out;                  // [64, 1, 128]

    float* hbuf = (float*)d_ws;                  // [2][BB][HH] ping-pong
    const size_t hbuf_elems = 2ull * BB * HH;
    const size_t hbuf_bytes = hbuf_elems * sizeof(float);
    unsigned* bar = (unsigned*)(hbuf + hbuf_elems);   // cnt[4], gen[4]

    if (ws_size >= hbuf_bytes + 8 * sizeof(unsigned)) {
        hipMemsetAsync(hbuf, 0, (size_t)BB * HH * sizeof(float), stream);  // h_0 = 0
        hipMemsetAsync(bar, 0, 8 * sizeof(unsigned), stream);              // barriers
        unsigned* bar_cnt = bar;
        unsigned* bar_gen = bar + 4;
        void* args[7];
        args[0] = (void*)&x;       args[1] = (void*)&tf;
        args[2] = (void*)&W;       args[3] = (void*)&brnn;
        args[4] = (void*)&hbuf;    args[5] = (void*)&bar_cnt;
        args[6] = (void*)&bar_gen;
        hipError_t e = hipLaunchCooperativeKernel(
            reinterpret_cast<void*>(rnn_persist2), dim3(256), dim3(512),
            args, 0, stream);
        if (e == hipSuccess) {
            rnn_out<<<BB, 128, 0, stream>>>(hbuf /* parity 0 after 512 steps */,
                                            Wout, bout, out);
            return;
        }
        (void)hipGetLastError();   // clear sticky error, fall back
    }

    if (ws_size < hbuf_bytes) {
        rnn_scan_kernel<<<BB, 512, 0, stream>>>(x, tf, W, brnn, Wout, bout, out);
        return;
    }
    // R5 proven multi-launch path
    hipMemsetAsync(hbuf, 0, (size_t)BB * HH * sizeof(float), stream);
    for (int t = 0; t < TT; ++t) {
        rnn_step2<<<256, 512, 0, stream>>>(x, tf, W, brnn,
                                           hbuf + (size_t)(t & 1) * BB * HH,
                                           hbuf + (size_t)((t + 1) & 1) * BB * HH,
                                           t);
    }
    rnn_out<<<BB, 128, 0, stream>>>(hbuf, Wout, bout, out);
}

// Round 7
// 3060.926 us; speedup vs baseline: 9.7494x; 9.7494x over previous
//
#include <hip/hip_runtime.h>
#include <math.h>

#define BB   64      // batch
#define TT   512     // time steps
#define CIN  32
#define THF  32
#define HH   1024    // hidden
#define LL   128
#define INF  64      // CIN + THF
#define KD   1088    // INF + HH
#define SR2  1096    // s row stride (floats): %32==8 -> strided-row b128 reads land 2-per-bank-slot (free)

// ================= per-step kernel (R7) =================
// grid 256 = 4 bg x 64 cg (bid%8 == cg%8 -> per-XCD W slice = 128 cols = 557KB, L2-resident).
// 512 threads: q = tid>>4 (32 k-slices of 36 rows), bb = (tid>>2)&3, cc = tid&3.
// Thread computes 4 batches {bb,bb+4,bb+8,bb+12} x 4 cols {c0+4cc..+3}:
// 16 accumulators, s from LDS (broadcast), W straight from L2 (no staging).
__global__ __launch_bounds__(512, 2)
void rnn_step3(const float* __restrict__ x, const float* __restrict__ tfeat,
               const float* __restrict__ W,     // [KD][HH] row-major
               const float* __restrict__ bias,  // [HH]
               const float* __restrict__ hprev, // [BB][HH]
               float* __restrict__ hnext,       // [BB][HH]
               int t)
{
    __shared__ float s[16 * SR2];     // [16 batches][inputs(64)|h(1024)] (+pad)
    __shared__ float zr[8][16][17];   // [wave][batch][col] partials

    const int tid = threadIdx.x;
    const int bid = blockIdx.x;
    const int bg  = bid >> 6;         // 0..3
    const int cg  = bid & 63;         // 0..63
    const int b0  = bg * 16;
    const int c0  = cg * 16;

    const int q   = tid >> 4;         // 0..31 k-slice
    const int bb  = (tid >> 2) & 3;   // batch sub
    const int cc  = tid & 3;          // col sub
    const int k0  = q * 36;

    // ---- stage h_prev: 16 x 1024 floats = 4096 float4, fully coalesced ----
    const float4* hp4 = reinterpret_cast<const float4*>(hprev) + (size_t)b0 * 256;
    #pragma unroll
    for (int jj = 0; jj < 8; ++jj) {
        int f = tid + 512 * jj;       // 0..4095
        int b = f >> 8, c = f & 255;
        float4 v = hp4[f];
        *reinterpret_cast<float4*>(&s[b * SR2 + INF + 4 * c]) = v;
    }
    // ---- stage step-t inputs: 16 x 64 floats ----
    if (tid < 256) {
        int b = tid >> 4, jf = tid & 15;
        float4 v;
        if (jf < 8)
            v = *reinterpret_cast<const float4*>(&x[((size_t)(b0 + b) * TT + t) * CIN + jf * 4]);
        else
            v = *reinterpret_cast<const float4*>(&tfeat[((size_t)(b0 + b) * TT + t) * THF + (jf - 8) * 4]);
        *reinterpret_cast<float4*>(&s[b * SR2 + jf * 4]) = v;
    }
    __syncthreads();

    // valid float4-iters in this thread's k-range [k0, k0+36): q<=29 -> 9, q=30 -> 2, q=31 -> 0
    int nj = 0;
    if (k0 < KD) { int rem = KD - k0; nj = (rem >= 36) ? 9 : (rem >> 2); }

    const float* wp = W + (size_t)k0 * HH + c0 + 4 * cc;
    const float* sp = s + k0;

    float4 acc0 = {0.f,0.f,0.f,0.f}, acc1 = {0.f,0.f,0.f,0.f};
    float4 acc2 = {0.f,0.f,0.f,0.f}, acc3 = {0.f,0.f,0.f,0.f};

#define FMA4(A, sv, wv) \
    A.x = fmaf(sv, wv.x, A.x); A.y = fmaf(sv, wv.y, A.y); \
    A.z = fmaf(sv, wv.z, A.z); A.w = fmaf(sv, wv.w, A.w);

    #pragma unroll 2
    for (int j = 0; j < nj; ++j) {
        float4 w0 = *reinterpret_cast<const float4*>(wp + (size_t)(4 * j + 0) * HH);
        float4 w1 = *reinterpret_cast<const float4*>(wp + (size_t)(4 * j + 1) * HH);
        float4 w2 = *reinterpret_cast<const float4*>(wp + (size_t)(4 * j + 2) * HH);
        float4 w3 = *reinterpret_cast<const float4*>(wp + (size_t)(4 * j + 3) * HH);
        float4 s0 = *reinterpret_cast<const float4*>(sp + (bb +  0) * SR2 + 4 * j);
        float4 s1 = *reinterpret_cast<const float4*>(sp + (bb +  4) * SR2 + 4 * j);
        float4 s2 = *reinterpret_cast<const float4*>(sp + (bb +  8) * SR2 + 4 * j);
        float4 s3 = *reinterpret_cast<const float4*>(sp + (bb + 12) * SR2 + 4 * j);
        FMA4(acc0, s0.x, w0) FMA4(acc0, s0.y, w1) FMA4(acc0, s0.z, w2) FMA4(acc0, s0.w, w3)
        FMA4(acc1, s1.x, w0) FMA4(acc1, s1.y, w1) FMA4(acc1, s1.z, w2) FMA4(acc1, s1.w, w3)
        FMA4(acc2, s2.x, w0) FMA4(acc2, s2.y, w1) FMA4(acc2, s2.z, w2) FMA4(acc2, s2.w, w3)
        FMA4(acc3, s3.x, w0) FMA4(acc3, s3.y, w1) FMA4(acc3, s3.z, w2) FMA4(acc3, s3.w, w3)
    }
#undef FMA4

    // ---- in-wave reduce over the 4 q-slices sharing a wave (lane bits 4,5) ----
#define REDSTEP(A, D) \
    A.x += __shfl_xor(A.x, D); A.y += __shfl_xor(A.y, D); \
    A.z += __shfl_xor(A.z, D); A.w += __shfl_xor(A.w, D);
    REDSTEP(acc0, 16) REDSTEP(acc1, 16) REDSTEP(acc2, 16) REDSTEP(acc3, 16)
    REDSTEP(acc0, 32) REDSTEP(acc1, 32) REDSTEP(acc2, 32) REDSTEP(acc3, 32)
#undef REDSTEP

    if ((tid & 48) == 0) {            // one lane per (wave, bb, cc)
        int w = tid >> 6;             // 0..7
        zr[w][bb +  0][4*cc+0] = acc0.x; zr[w][bb +  0][4*cc+1] = acc0.y;
        zr[w][bb +  0][4*cc+2] = acc0.z; zr[w][bb +  0][4*cc+3] = acc0.w;
        zr[w][bb +  4][4*cc+0] = acc1.x; zr[w][bb +  4][4*cc+1] = acc1.y;
        zr[w][bb +  4][4*cc+2] = acc1.z; zr[w][bb +  4][4*cc+3] = acc1.w;
        zr[w][bb +  8][4*cc+0] = acc2.x; zr[w][bb +  8][4*cc+1] = acc2.y;
        zr[w][bb +  8][4*cc+2] = acc2.z; zr[w][bb +  8][4*cc+3] = acc2.w;
        zr[w][bb + 12][4*cc+0] = acc3.x; zr[w][bb + 12][4*cc+1] = acc3.y;
        zr[w][bb + 12][4*cc+2] = acc3.z; zr[w][bb + 12][4*cc+3] = acc3.w;
    }
    __syncthreads();

    // ---- final 8-way reduce + bias + tanh + coalesced write ----
    if (tid < 256) {
        int b = tid >> 4, c = tid & 15;
        float z = bias[c0 + c];
        #pragma unroll
        for (int g = 0; g < 8; ++g) z += zr[g][b][c];
        hnext[(size_t)(b0 + b) * HH + c0 + c] = tanhf(z);
    }
}

// ================= epilogue =================
__global__ __launch_bounds__(128)
void rnn_out(const float* __restrict__ h, const float* __restrict__ Wout,
             const float* __restrict__ bout, float* __restrict__ out)
{
    __shared__ float hl[HH];
    const int b = blockIdx.x, tid = threadIdx.x;
    for (int i = tid; i < HH / 4; i += 128)
        *reinterpret_cast<float4*>(hl + 4 * i) =
            *reinterpret_cast<const float4*>(h + (size_t)b * HH + 4 * i);
    __syncthreads();
    float a0 = bout[tid], a1 = 0.f, a2 = 0.f, a3 = 0.f;
    for (int j = 0; j < HH; j += 4) {
        a0 = fmaf(hl[j + 0], Wout[(size_t)(j + 0) * LL + tid], a0);
        a1 = fmaf(hl[j + 1], Wout[(size_t)(j + 1) * LL + tid], a1);
        a2 = fmaf(hl[j + 2], Wout[(size_t)(j + 2) * LL + tid], a2);
        a3 = fmaf(hl[j + 3], Wout[(size_t)(j + 3) * LL + tid], a3);
    }
    out[(size_t)b * LL + tid] = (a0 + a1) + (a2 + a3);
}

// ================= tiny-ws fallback (R1, proven) =================
__global__ __launch_bounds__(512)
void rnn_scan_kernel(const float* __restrict__ x, const float* __restrict__ tf,
                     const float* __restrict__ W, const float* __restrict__ bias,
                     const float* __restrict__ Wout, const float* __restrict__ bout,
                     float* __restrict__ out)
{
    __shared__ float s[KD];
    const int b_idx = blockIdx.x, tid = threadIdx.x;
    if (tid < CIN)      s[tid] = x[b_idx * TT * CIN + tid];
    else if (tid < INF) s[tid] = tf[b_idx * TT * THF + (tid - CIN)];
    for (int i = tid; i < HH; i += 512) s[INF + i] = 0.0f;
    __syncthreads();
    const int j0 = tid * 2;
    const float bias0 = bias[j0], bias1 = bias[j0 + 1];
    for (int t = 0; t < TT; ++t) {
        float z0 = bias0, z1 = bias1;
        #pragma unroll 8
        for (int k = 0; k < KD; ++k) {
            const float2 wv = *reinterpret_cast<const float2*>(&W[(size_t)k * HH + j0]);
            const float sv = s[k];
            z0 = fmaf(sv, wv.x, z0);
            z1 = fmaf(sv, wv.y, z1);
        }
        float nin = 0.0f;
        const int tn = t + 1;
        if (tn < TT) {
            if (tid < CIN)      nin = x[b_idx * TT * CIN + tn * CIN + tid];
            else if (tid < INF) nin = tf[b_idx * TT * THF + tn * THF + (tid - CIN)];
        }
        __syncthreads();
        s[INF + j0]     = tanhf(z0);
        s[INF + j0 + 1] = tanhf(z1);
        if (tid < INF && tn < TT) s[tid] = nin;
        __syncthreads();
    }
    for (int lll = tid; lll < LL; lll += 512) {
        float acc = bout[lll];
        for (int j = 0; j < HH; ++j) acc = fmaf(s[INF + j], Wout[(size_t)j * LL + lll], acc);
        out[(size_t)b_idx * LL + lll] = acc;
    }
}

extern "C" void kernel_launch(void* const* d_in, const int* in_sizes, int n_in,
                              void* d_out, int out_size, void* d_ws, size_t ws_size,
                              hipStream_t stream) {
    const float* x    = (const float*)d_in[0];   // [64, 512, 32]
    const float* tf   = (const float*)d_in[1];   // [64, 512, 32]
    const float* W    = (const float*)d_in[2];   // [1088, 1024]
    const float* brnn = (const float*)d_in[3];   // [1024]
    const float* Wout = (const float*)d_in[4];   // [1024, 128]
    const float* bout = (const float*)d_in[5];   // [128]
    float* out = (float*)d_out;                  // [64, 1, 128]

    float* hbuf = (float*)d_ws;                  // [2][BB][HH] ping-pong
    const size_t hbuf_bytes = 2ull * BB * HH * sizeof(float);

    if (ws_size < hbuf_bytes) {
        rnn_scan_kernel<<<BB, 512, 0, stream>>>(x, tf, W, brnn, Wout, bout, out);
        return;
    }

    hipMemsetAsync(hbuf, 0, (size_t)BB * HH * sizeof(float), stream);  // h_0 = 0
    for (int t = 0; t < TT; ++t) {
        rnn_step3<<<256, 512, 0, stream>>>(x, tf, W, brnn,
                                           hbuf + (size_t)(t & 1) * BB * HH,
                                           hbuf + (size_t)((t + 1) & 1) * BB * HH,
                                           t);
    }
    // after 512 steps final h is at parity 0
    rnn_out<<<BB, 128, 0, stream>>>(hbuf, Wout, bout, out);
}

// Round 8
// 2048.493 us; speedup vs baseline: 14.5678x; 1.4942x over previous
//
#include <hip/hip_runtime.h>
#include <math.h>

#define BB   64      // batch
#define TT   512     // time steps
#define CIN  32
#define THF  32
#define HH   1024    // hidden
#define LL   128
#define INF  64      // CIN + THF
#define KD   1088    // INF + HH
#define KP   1096    // bf16 row stride (elems): 2192 B -> rows offset 4 banks, b128 reads spread
#define SR2  1096    // fp32 fallback stride

typedef short  short8 __attribute__((ext_vector_type(8)));   // 8 bf16 = 4 VGPRs
typedef float  f32x4  __attribute__((ext_vector_type(4)));

static __device__ __forceinline__ unsigned short f2bf(float f) {   // RNE
    union { float f; unsigned u; } v; v.f = f;
    return (unsigned short)((v.u + 0x7fffu + ((v.u >> 16) & 1u)) >> 16);
}
static __device__ __forceinline__ float bf2f(unsigned short h) {
    union { unsigned u; float f; } v; v.u = ((unsigned)h) << 16;
    return v.f;
}

// ---------- one-time: W[KD][HH] fp32 -> Wt[HH][KP] bf16 (k-contiguous) ----------
__global__ __launch_bounds__(256)
void transposeW_bf16(const float* __restrict__ W, unsigned short* __restrict__ Wt) {
    __shared__ float tile[32][33];
    const int ct = blockIdx.x * 32;    // col tile (0..1023)
    const int kt = blockIdx.y * 32;    // k tile   (0..1087)
    for (int i = threadIdx.y; i < 32; i += 8)
        tile[i][threadIdx.x] = W[(size_t)(kt + i) * HH + ct + threadIdx.x];
    __syncthreads();
    for (int i = threadIdx.y; i < 32; i += 8)
        Wt[(size_t)(ct + i) * KP + kt + threadIdx.x] = f2bf(tile[threadIdx.x][i]);
}

template<int N>
static __device__ __forceinline__ f32x4 kchunk(const short8* __restrict__ arow,
                                               const short8* __restrict__ brow,
                                               int start, int lg, f32x4 acc) {
    short8 bfr[N];
    #pragma unroll
    for (int i = 0; i < N; ++i) bfr[i] = brow[(start + i) * 4 + lg];   // W frags from L2
    #pragma unroll
    for (int i = 0; i < N; ++i) {
        short8 afr = arow[(start + i) * 4 + lg];                       // s frags from LDS
        acc = __builtin_amdgcn_mfma_f32_16x16x32_bf16(afr, bfr[i], acc, 0, 0, 0);
    }
    return acc;
}

// ---------- per-step MFMA kernel ----------
// grid 256 = 4 bg x 64 cg (bid%8==cg%8 -> XCD-local W slice). 256 thr = 4 waves.
// Wave w: K-chunk {9,9,8,8} MFMAs of 16x16x32; A = s[batch][k] (LDS bf16),
// B = Wt[col][k] (global bf16, L2-resident). D: col=lane&15, row=(lane>>4)*4+reg.
__global__ __launch_bounds__(256)
void rnn_step_mfma(const float* __restrict__ x, const float* __restrict__ tfeat,
                   const unsigned short* __restrict__ Wt,    // [HH][KP] bf16
                   const float* __restrict__ bias,
                   const unsigned short* __restrict__ hprev, // [BB][HH] bf16
                   unsigned short* __restrict__ hnext,       // [BB][HH] bf16
                   int t)
{
    __shared__ unsigned short s_lds[16 * KP];   // [16 batches][inputs(64)|h(1024)] bf16
    __shared__ float zr[4][16][16];             // per-wave partial C tiles

    const int tid = threadIdx.x;
    const int bid = blockIdx.x;
    const int bg  = bid >> 6, cg = bid & 63;
    const int b0  = bg * 16,  c0 = cg * 16;
    const int w   = tid >> 6, lane = tid & 63;
    const int l15 = lane & 15, lg = lane >> 4;

    // ---- stage h (bf16): 16 x 1024 = 2048 ushort8 chunks, coalesced 16B ----
    {
        const short8* hp8 = (const short8*)(hprev + (size_t)b0 * HH);
        #pragma unroll
        for (int it = 0; it < 8; ++it) {
            int i = tid + 256 * it;              // 0..2047
            int row = i >> 7, ch = i & 127;
            short8 v = hp8[row * 128 + ch];
            *(short8*)&s_lds[row * KP + INF + ch * 8] = v;
        }
    }
    // ---- stage step-t inputs: 16 x 64 fp32 -> bf16 ----
    {
        int b = tid >> 4, jf = tid & 15;
        float4 v;
        if (jf < 8) v = *(const float4*)&x[((size_t)(b0 + b) * TT + t) * CIN + jf * 4];
        else        v = *(const float4*)&tfeat[((size_t)(b0 + b) * TT + t) * THF + (jf - 8) * 4];
        ushort4 pk = make_ushort4(f2bf(v.x), f2bf(v.y), f2bf(v.z), f2bf(v.w));
        *(ushort4*)&s_lds[b * KP + jf * 4] = pk;
    }
    __syncthreads();

    const short8* arow = (const short8*)&s_lds[l15 * KP];            // batch row
    const short8* brow = (const short8*)&Wt[(size_t)(c0 + l15) * KP]; // col row
    f32x4 acc = {0.f, 0.f, 0.f, 0.f};
    if (w < 2) acc = kchunk<9>(arow, brow, w * 9, lg, acc);
    else       acc = kchunk<8>(arow, brow, 18 + (w - 2) * 8, lg, acc);

    #pragma unroll
    for (int r = 0; r < 4; ++r) zr[w][lg * 4 + r][l15] = acc[r];
    __syncthreads();

    // ---- 4-way reduce + bias + tanh + bf16 store ----
    {
        int b = tid >> 4, c = tid & 15;
        float z = bias[c0 + c] + zr[0][b][c] + zr[1][b][c] + zr[2][b][c] + zr[3][b][c];
        hnext[(size_t)(b0 + b) * HH + c0 + c] = f2bf(tanhf(z));
    }
}

// ---------- epilogue (bf16 h) ----------
__global__ __launch_bounds__(128)
void rnn_out_bf16(const unsigned short* __restrict__ h, const float* __restrict__ Wout,
                  const float* __restrict__ bout, float* __restrict__ out)
{
    __shared__ float hl[HH];
    const int b = blockIdx.x, tid = threadIdx.x;
    {
        const short8* hp8 = (const short8*)(h + (size_t)b * HH);
        short8 v = hp8[tid];                    // 128 chunks of 8
        #pragma unroll
        for (int j = 0; j < 8; ++j) hl[tid * 8 + j] = bf2f((unsigned short)v[j]);
    }
    __syncthreads();
    float a0 = bout[tid], a1 = 0.f, a2 = 0.f, a3 = 0.f;
    for (int j = 0; j < HH; j += 4) {
        a0 = fmaf(hl[j + 0], Wout[(size_t)(j + 0) * LL + tid], a0);
        a1 = fmaf(hl[j + 1], Wout[(size_t)(j + 1) * LL + tid], a1);
        a2 = fmaf(hl[j + 2], Wout[(size_t)(j + 2) * LL + tid], a2);
        a3 = fmaf(hl[j + 3], Wout[(size_t)(j + 3) * LL + tid], a3);
    }
    out[(size_t)b * LL + tid] = (a0 + a1) + (a2 + a3);
}

// ================= fp32 fallback path (R7, proven 3.06 ms) =================
__global__ __launch_bounds__(512, 2)
void rnn_step3(const float* __restrict__ x, const float* __restrict__ tfeat,
               const float* __restrict__ W, const float* __restrict__ bias,
               const float* __restrict__ hprev, float* __restrict__ hnext, int t)
{
    __shared__ float s[16 * SR2];
    __shared__ float zr[8][16][17];
    const int tid = threadIdx.x;
    const int bid = blockIdx.x;
    const int bg = bid >> 6, cg = bid & 63;
    const int b0 = bg * 16, c0 = cg * 16;
    const int q = tid >> 4, bb = (tid >> 2) & 3, cc = tid & 3;
    const int k0 = q * 36;

    const float4* hp4 = reinterpret_cast<const float4*>(hprev) + (size_t)b0 * 256;
    #pragma unroll
    for (int jj = 0; jj < 8; ++jj) {
        int f = tid + 512 * jj;
        int b = f >> 8, c = f & 255;
        float4 v = hp4[f];
        *reinterpret_cast<float4*>(&s[b * SR2 + INF + 4 * c]) = v;
    }
    if (tid < 256) {
        int b = tid >> 4, jf = tid & 15;
        float4 v;
        if (jf < 8) v = *reinterpret_cast<const float4*>(&x[((size_t)(b0 + b) * TT + t) * CIN + jf * 4]);
        else        v = *reinterpret_cast<const float4*>(&tfeat[((size_t)(b0 + b) * TT + t) * THF + (jf - 8) * 4]);
        *reinterpret_cast<float4*>(&s[b * SR2 + jf * 4]) = v;
    }
    __syncthreads();

    int nj = 0;
    if (k0 < KD) { int rem = KD - k0; nj = (rem >= 36) ? 9 : (rem >> 2); }
    const float* wp = W + (size_t)k0 * HH + c0 + 4 * cc;
    const float* sp = s + k0;
    float4 acc0 = {0,0,0,0}, acc1 = {0,0,0,0}, acc2 = {0,0,0,0}, acc3 = {0,0,0,0};
#define FMA4(A, sv, wv) \
    A.x = fmaf(sv, wv.x, A.x); A.y = fmaf(sv, wv.y, A.y); \
    A.z = fmaf(sv, wv.z, A.z); A.w = fmaf(sv, wv.w, A.w);
    #pragma unroll 2
    for (int j = 0; j < nj; ++j) {
        float4 w0 = *reinterpret_cast<const float4*>(wp + (size_t)(4 * j + 0) * HH);
        float4 w1 = *reinterpret_cast<const float4*>(wp + (size_t)(4 * j + 1) * HH);
        float4 w2 = *reinterpret_cast<const float4*>(wp + (size_t)(4 * j + 2) * HH);
        float4 w3 = *reinterpret_cast<const float4*>(wp + (size_t)(4 * j + 3) * HH);
        float4 s0 = *reinterpret_cast<const float4*>(sp + (bb +  0) * SR2 + 4 * j);
        float4 s1 = *reinterpret_cast<const float4*>(sp + (bb +  4) * SR2 + 4 * j);
        float4 s2 = *reinterpret_cast<const float4*>(sp + (bb +  8) * SR2 + 4 * j);
        float4 s3 = *reinterpret_cast<const float4*>(sp + (bb + 12) * SR2 + 4 * j);
        FMA4(acc0, s0.x, w0) FMA4(acc0, s0.y, w1) FMA4(acc0, s0.z, w2) FMA4(acc0, s0.w, w3)
        FMA4(acc1, s1.x, w0) FMA4(acc1, s1.y, w1) FMA4(acc1, s1.z, w2) FMA4(acc1, s1.w, w3)
        FMA4(acc2, s2.x, w0) FMA4(acc2, s2.y, w1) FMA4(acc2, s2.z, w2) FMA4(acc2, s2.w, w3)
        FMA4(acc3, s3.x, w0) FMA4(acc3, s3.y, w1) FMA4(acc3, s3.z, w2) FMA4(acc3, s3.w, w3)
    }
#undef FMA4
#define REDSTEP(A, D) \
    A.x += __shfl_xor(A.x, D); A.y += __shfl_xor(A.y, D); \
    A.z += __shfl_xor(A.z, D); A.w += __shfl_xor(A.w, D);
    REDSTEP(acc0, 16) REDSTEP(acc1, 16) REDSTEP(acc2, 16) REDSTEP(acc3, 16)
    REDSTEP(acc0, 32) REDSTEP(acc1, 32) REDSTEP(acc2, 32) REDSTEP(acc3, 32)
#undef REDSTEP
    if ((tid & 48) == 0) {
        int ww = tid >> 6;
        zr[ww][bb +  0][4*cc+0] = acc0.x; zr[ww][bb +  0][4*cc+1] = acc0.y;
        zr[ww][bb +  0][4*cc+2] = acc0.z; zr[ww][bb +  0][4*cc+3] = acc0.w;
        zr[ww][bb +  4][4*cc+0] = acc1.x; zr[ww][bb +  4][4*cc+1] = acc1.y;
        zr[ww][bb +  4][4*cc+2] = acc1.z; zr[ww][bb +  4][4*cc+3] = acc1.w;
        zr[ww][bb +  8][4*cc+0] = acc2.x; zr[ww][bb +  8][4*cc+1] = acc2.y;
        zr[ww][bb +  8][4*cc+2] = acc2.z; zr[ww][bb +  8][4*cc+3] = acc2.w;
        zr[ww][bb + 12][4*cc+0] = acc3.x; zr[ww][bb + 12][4*cc+1] = acc3.y;
        zr[ww][bb + 12][4*cc+2] = acc3.z; zr[ww][bb + 12][4*cc+3] = acc3.w;
    }
    __syncthreads();
    if (tid < 256) {
        int b = tid >> 4, c = tid & 15;
        float z = bias[c0 + c];
        #pragma unroll
        for (int g = 0; g < 8; ++g) z += zr[g][b][c];
        hnext[(size_t)(b0 + b) * HH + c0 + c] = tanhf(z);
    }
}

__global__ __launch_bounds__(128)
void rnn_out(const float* __restrict__ h, const float* __restrict__ Wout,
             const float* __restrict__ bout, float* __restrict__ out)
{
    __shared__ float hl[HH];
    const int b = blockIdx.x, tid = threadIdx.x;
    for (int i = tid; i < HH / 4; i += 128)
        *reinterpret_cast<float4*>(hl + 4 * i) =
            *reinterpret_cast<const float4*>(h + (size_t)b * HH + 4 * i);
    __syncthreads();
    float a0 = bout[tid], a1 = 0.f, a2 = 0.f, a3 = 0.f;
    for (int j = 0; j < HH; j += 4) {
        a0 = fmaf(hl[j + 0], Wout[(size_t)(j + 0) * LL + tid], a0);
        a1 = fmaf(hl[j + 1], Wout[(size_t)(j + 1) * LL + tid], a1);
        a2 = fmaf(hl[j + 2], Wout[(size_t)(j + 2) * LL + tid], a2);
        a3 = fmaf(hl[j + 3], Wout[(size_t)(j + 3) * LL + tid], a3);
    }
    out[(size_t)b * LL + tid] = (a0 + a1) + (a2 + a3);
}

__global__ __launch_bounds__(512)
void rnn_scan_kernel(const float* __restrict__ x, const float* __restrict__ tf,
                     const float* __restrict__ W, const float* __restrict__ bias,
                     const float* __restrict__ Wout, const float* __restrict__ bout,
                     float* __restrict__ out)
{
    __shared__ float s[KD];
    const int b_idx = blockIdx.x, tid = threadIdx.x;
    if (tid < CIN)      s[tid] = x[b_idx * TT * CIN + tid];
    else if (tid < INF) s[tid] = tf[b_idx * TT * THF + (tid - CIN)];
    for (int i = tid; i < HH; i += 512) s[INF + i] = 0.0f;
    __syncthreads();
    const int j0 = tid * 2;
    const float bias0 = bias[j0], bias1 = bias[j0 + 1];
    for (int t = 0; t < TT; ++t) {
        float z0 = bias0, z1 = bias1;
        #pragma unroll 8
        for (int k = 0; k < KD; ++k) {
            const float2 wv = *reinterpret_cast<const float2*>(&W[(size_t)k * HH + j0]);
            const float sv = s[k];
            z0 = fmaf(sv, wv.x, z0);
            z1 = fmaf(sv, wv.y, z1);
        }
        float nin = 0.0f;
        const int tn = t + 1;
        if (tn < TT) {
            if (tid < CIN)      nin = x[b_idx * TT * CIN + tn * CIN + tid];
            else if (tid < INF) nin = tf[b_idx * TT * THF + tn * THF + (tid - CIN)];
        }
        __syncthreads();
        s[INF + j0]     = tanhf(z0);
        s[INF + j0 + 1] = tanhf(z1);
        if (tid < INF && tn < TT) s[tid] = nin;
        __syncthreads();
    }
    for (int lll = tid; lll < LL; lll += 512) {
        float acc = bout[lll];
        for (int j = 0; j < HH; ++j) acc = fmaf(s[INF + j], Wout[(size_t)j * LL + lll], acc);
        out[(size_t)b_idx * LL + lll] = acc;
    }
}

extern "C" void kernel_launch(void* const* d_in, const int* in_sizes, int n_in,
                              void* d_out, int out_size, void* d_ws, size_t ws_size,
                              hipStream_t stream) {
    const float* x    = (const float*)d_in[0];   // [64, 512, 32]
    const float* tf   = (const float*)d_in[1];   // [64, 512, 32]
    const float* W    = (const float*)d_in[2];   // [1088, 1024]
    const float* brnn = (const float*)d_in[3];   // [1024]
    const float* Wout = (const float*)d_in[4];   // [1024, 128]
    const float* bout = (const float*)d_in[5];   // [128]
    float* out = (float*)d_out;                  // [64, 1, 128]

    // ---- MFMA bf16 path ----
    const size_t hbf_bytes = 2ull * BB * HH * sizeof(unsigned short);      // 256 KB
    const size_t wt_bytes  = (size_t)HH * KP * sizeof(unsigned short);     // ~2.24 MB
    if (ws_size >= hbf_bytes + wt_bytes) {
        unsigned short* hbf = (unsigned short*)d_ws;            // [2][BB][HH] bf16
        unsigned short* Wt  = hbf + 2ull * BB * HH;             // [HH][KP] bf16
        hipMemsetAsync(hbf, 0, (size_t)BB * HH * sizeof(unsigned short), stream);
        transposeW_bf16<<<dim3(HH / 32, KD / 32), dim3(32, 8), 0, stream>>>(W, Wt);
        for (int t = 0; t < TT; ++t) {
            rnn_step_mfma<<<256, 256, 0, stream>>>(x, tf, Wt, brnn,
                hbf + (size_t)(t & 1) * BB * HH,
                hbf + (size_t)((t + 1) & 1) * BB * HH, t);
        }
        rnn_out_bf16<<<BB, 128, 0, stream>>>(hbf /* parity 0 */, Wout, bout, out);
        return;
    }

    // ---- fp32 fallback (R7 path) ----
    float* hbuf = (float*)d_ws;
    const size_t hbuf_bytes = 2ull * BB * HH * sizeof(float);
    if (ws_size < hbuf_bytes) {
        rnn_scan_kernel<<<BB, 512, 0, stream>>>(x, tf, W, brnn, Wout, bout, out);
        return;
    }
    hipMemsetAsync(hbuf, 0, (size_t)BB * HH * sizeof(float), stream);
    for (int t = 0; t < TT; ++t) {
        rnn_step3<<<256, 512, 0, stream>>>(x, tf, W, brnn,
                                           hbuf + (size_t)(t & 1) * BB * HH,
                                           hbuf + (size_t)((t + 1) & 1) * BB * HH,
                                           t);
    }
    rnn_out<<<BB, 128, 0, stream>>>(hbuf, Wout, bout, out);
}

// Round 9
// 1882.520 us; speedup vs baseline: 15.8522x; 1.0882x over previous
//
#include <hip/hip_runtime.h>
#include <math.h>

#define BB   64      // batch
#define TT   512     // time steps
#define CIN  32
#define THF  32
#define HH   1024    // hidden
#define LL   128
#define INF  64      // CIN + THF
#define KD   1088    // INF + KD rows of W_rnn
#define KP   1096    // bf16 Wt row stride (elems); 2192 B, 16B-aligned
#define SR2  1096    // fp32 fallback stride

typedef short  short8 __attribute__((ext_vector_type(8)));   // 8 bf16 = 4 VGPRs
typedef float  f32x4  __attribute__((ext_vector_type(4)));

static __device__ __forceinline__ unsigned short f2bf(float f) {   // RNE
    union { float f; unsigned u; } v; v.f = f;
    return (unsigned short)((v.u + 0x7fffu + ((v.u >> 16) & 1u)) >> 16);
}
static __device__ __forceinline__ float bf2f(unsigned short h) {
    union { unsigned u; float f; } v; v.u = ((unsigned)h) << 16;
    return v.f;
}

// ---------- one-time: W[KD][HH] fp32 -> Wt[HH][KP] bf16 (k-contiguous) ----------
__global__ __launch_bounds__(256)
void transposeW_bf16(const float* __restrict__ W, unsigned short* __restrict__ Wt) {
    __shared__ float tile[32][33];
    const int ct = blockIdx.x * 32;    // col tile
    const int kt = blockIdx.y * 32;    // k tile
    for (int i = threadIdx.y; i < 32; i += 8)
        tile[i][threadIdx.x] = W[(size_t)(kt + i) * HH + ct + threadIdx.x];
    __syncthreads();
    for (int i = threadIdx.y; i < 32; i += 8)
        Wt[(size_t)(ct + i) * KP + kt + threadIdx.x] = f2bf(tile[threadIdx.x][i]);
}

// ---------- per-wave K-chunk: all frags straight from global (L2-hot) ----------
// chunk c covers k = c*32..c*32+31. c==0 -> x (fp32->bf16), c==1 -> tfeat,
// c>=2 -> hprev bf16. A-frag lane row = b0+l15, 16B at k-offset lg*8.
template<int Start, int Count>
static __device__ __forceinline__ f32x4
waveK(const float* __restrict__ x, const float* __restrict__ tfeat,
      const unsigned short* __restrict__ hprev, const short8* __restrict__ brow,
      int b0, int l15, int lg, int t, f32x4 acc)
{
    short8 bf[Count], af[Count];
    #pragma unroll
    for (int i = 0; i < Count; ++i) bf[i] = brow[(Start + i) * 4 + lg];   // W frags
    #pragma unroll
    for (int i = 0; i < Count; ++i) {
        if (Start + i == 0) {            // k 0..31: x features, convert
            const float* xp = &x[((size_t)(b0 + l15) * TT + t) * CIN + lg * 8];
            float4 v0 = *(const float4*)xp, v1 = *(const float4*)(xp + 4);
            short8 a;
            a[0] = (short)f2bf(v0.x); a[1] = (short)f2bf(v0.y);
            a[2] = (short)f2bf(v0.z); a[3] = (short)f2bf(v0.w);
            a[4] = (short)f2bf(v1.x); a[5] = (short)f2bf(v1.y);
            a[6] = (short)f2bf(v1.z); a[7] = (short)f2bf(v1.w);
            af[i] = a;
        } else if (Start + i == 1) {     // k 32..63: t features, convert
            const float* tp = &tfeat[((size_t)(b0 + l15) * TT + t) * THF + lg * 8];
            float4 v0 = *(const float4*)tp, v1 = *(const float4*)(tp + 4);
            short8 a;
            a[0] = (short)f2bf(v0.x); a[1] = (short)f2bf(v0.y);
            a[2] = (short)f2bf(v0.z); a[3] = (short)f2bf(v0.w);
            a[4] = (short)f2bf(v1.x); a[5] = (short)f2bf(v1.y);
            a[6] = (short)f2bf(v1.z); a[7] = (short)f2bf(v1.w);
            af[i] = a;
        } else {                         // k>=64: h region, bf16 direct
            af[i] = ((const short8*)(hprev + (size_t)(b0 + l15) * HH))[(Start + i) * 4 + lg - 8];
        }
    }
    #pragma unroll
    for (int i = 0; i < Count; ++i)
        acc = __builtin_amdgcn_mfma_f32_16x16x32_bf16(af[i], bf[i], acc, 0, 0, 0);
    return acc;
}

// ---------- per-step MFMA kernel (no LDS staging) ----------
// grid 256 = 4 bg x 64 cg (bid%8==cg%8 -> XCD-local W slice). 256 thr = 4 waves.
// Wave w owns K-chunks {0-8, 9-17, 18-25, 26-33}; 4-way reduce in LDS.
__global__ __launch_bounds__(256)
void rnn_step_mfma(const float* __restrict__ x, const float* __restrict__ tfeat,
                   const unsigned short* __restrict__ Wt,    // [HH][KP] bf16
                   const float* __restrict__ bias,
                   const unsigned short* __restrict__ hprev, // [BB][HH] bf16
                   unsigned short* __restrict__ hnext,       // [BB][HH] bf16
                   int t)
{
    __shared__ float zr[4][16][16];

    const int tid = threadIdx.x;
    const int bid = blockIdx.x;
    const int bg  = bid >> 6, cg = bid & 63;
    const int b0  = bg * 16,  c0 = cg * 16;
    const int w   = tid >> 6, lane = tid & 63;
    const int l15 = lane & 15, lg = lane >> 4;

    const short8* brow = (const short8*)&Wt[(size_t)(c0 + l15) * KP];
    f32x4 acc = {0.f, 0.f, 0.f, 0.f};
    if      (w == 0) acc = waveK< 0, 9>(x, tfeat, hprev, brow, b0, l15, lg, t, acc);
    else if (w == 1) acc = waveK< 9, 9>(x, tfeat, hprev, brow, b0, l15, lg, t, acc);
    else if (w == 2) acc = waveK<18, 8>(x, tfeat, hprev, brow, b0, l15, lg, t, acc);
    else             acc = waveK<26, 8>(x, tfeat, hprev, brow, b0, l15, lg, t, acc);

    // D frag: col = l15, row = lg*4 + r
    #pragma unroll
    for (int r = 0; r < 4; ++r) zr[w][lg * 4 + r][l15] = acc[r];
    __syncthreads();

    // ---- 4-way reduce + bias + tanh + bf16 store (coalesced 16x16) ----
    {
        int b = tid >> 4, c = tid & 15;
        float z = bias[c0 + c] + zr[0][b][c] + zr[1][b][c] + zr[2][b][c] + zr[3][b][c];
        hnext[(size_t)(b0 + b) * HH + c0 + c] = f2bf(tanhf(z));
    }
}

// ---------- epilogue (bf16 h) ----------
__global__ __launch_bounds__(128)
void rnn_out_bf16(const unsigned short* __restrict__ h, const float* __restrict__ Wout,
                  const float* __restrict__ bout, float* __restrict__ out)
{
    __shared__ float hl[HH];
    const int b = blockIdx.x, tid = threadIdx.x;
    {
        const short8* hp8 = (const short8*)(h + (size_t)b * HH);
        short8 v = hp8[tid];
        #pragma unroll
        for (int j = 0; j < 8; ++j) hl[tid * 8 + j] = bf2f((unsigned short)v[j]);
    }
    __syncthreads();
    float a0 = bout[tid], a1 = 0.f, a2 = 0.f, a3 = 0.f;
    for (int j = 0; j < HH; j += 4) {
        a0 = fmaf(hl[j + 0], Wout[(size_t)(j + 0) * LL + tid], a0);
        a1 = fmaf(hl[j + 1], Wout[(size_t)(j + 1) * LL + tid], a1);
        a2 = fmaf(hl[j + 2], Wout[(size_t)(j + 2) * LL + tid], a2);
        a3 = fmaf(hl[j + 3], Wout[(size_t)(j + 3) * LL + tid], a3);
    }
    out[(size_t)b * LL + tid] = (a0 + a1) + (a2 + a3);
}

// ================= fp32 fallback path (R7, proven) =================
__global__ __launch_bounds__(512, 2)
void rnn_step3(const float* __restrict__ x, const float* __restrict__ tfeat,
               const float* __restrict__ W, const float* __restrict__ bias,
               const float* __restrict__ hprev, float* __restrict__ hnext, int t)
{
    __shared__ float s[16 * SR2];
    __shared__ float zr[8][16][17];
    const int tid = threadIdx.x;
    const int bid = blockIdx.x;
    const int bg = bid >> 6, cg = bid & 63;
    const int b0 = bg * 16, c0 = cg * 16;
    const int q = tid >> 4, bb = (tid >> 2) & 3, cc = tid & 3;
    const int k0 = q * 36;

    const float4* hp4 = reinterpret_cast<const float4*>(hprev) + (size_t)b0 * 256;
    #pragma unroll
    for (int jj = 0; jj < 8; ++jj) {
        int f = tid + 512 * jj;
        int b = f >> 8, c = f & 255;
        float4 v = hp4[f];
        *reinterpret_cast<float4*>(&s[b * SR2 + INF + 4 * c]) = v;
    }
    if (tid < 256) {
        int b = tid >> 4, jf = tid & 15;
        float4 v;
        if (jf < 8) v = *reinterpret_cast<const float4*>(&x[((size_t)(b0 + b) * TT + t) * CIN + jf * 4]);
        else        v = *reinterpret_cast<const float4*>(&tfeat[((size_t)(b0 + b) * TT + t) * THF + (jf - 8) * 4]);
        *reinterpret_cast<float4*>(&s[b * SR2 + jf * 4]) = v;
    }
    __syncthreads();

    int nj = 0;
    if (k0 < KD) { int rem = KD - k0; nj = (rem >= 36) ? 9 : (rem >> 2); }
    const float* wp = W + (size_t)k0 * HH + c0 + 4 * cc;
    const float* sp = s + k0;
    float4 acc0 = {0,0,0,0}, acc1 = {0,0,0,0}, acc2 = {0,0,0,0}, acc3 = {0,0,0,0};
#define FMA4(A, sv, wv) \
    A.x = fmaf(sv, wv.x, A.x); A.y = fmaf(sv, wv.y, A.y); \
    A.z = fmaf(sv, wv.z, A.z); A.w = fmaf(sv, wv.w, A.w);
    #pragma unroll 2
    for (int j = 0; j < nj; ++j) {
        float4 w0 = *reinterpret_cast<const float4*>(wp + (size_t)(4 * j + 0) * HH);
        float4 w1 = *reinterpret_cast<const float4*>(wp + (size_t)(4 * j + 1) * HH);
        float4 w2 = *reinterpret_cast<const float4*>(wp + (size_t)(4 * j + 2) * HH);
        float4 w3 = *reinterpret_cast<const float4*>(wp + (size_t)(4 * j + 3) * HH);
        float4 s0 = *reinterpret_cast<const float4*>(sp + (bb +  0) * SR2 + 4 * j);
        float4 s1 = *reinterpret_cast<const float4*>(sp + (bb +  4) * SR2 + 4 * j);
        float4 s2 = *reinterpret_cast<const float4*>(sp + (bb +  8) * SR2 + 4 * j);
        float4 s3 = *reinterpret_cast<const float4*>(sp + (bb + 12) * SR2 + 4 * j);
        FMA4(acc0, s0.x, w0) FMA4(acc0, s0.y, w1) FMA4(acc0, s0.z, w2) FMA4(acc0, s0.w, w3)
        FMA4(acc1, s1.x, w0) FMA4(acc1, s1.y, w1) FMA4(acc1, s1.z, w2) FMA4(acc1, s1.w, w3)
        FMA4(acc2, s2.x, w0) FMA4(acc2, s2.y, w1) FMA4(acc2, s2.z, w2) FMA4(acc2, s2.w, w3)
        FMA4(acc3, s3.x, w0) FMA4(acc3, s3.y, w1) FMA4(acc3, s3.z, w2) FMA4(acc3, s3.w, w3)
    }
#undef FMA4
#define REDSTEP(A, D) \
    A.x += __shfl_xor(A.x, D); A.y += __shfl_xor(A.y, D); \
    A.z += __shfl_xor(A.z, D); A.w += __shfl_xor(A.w, D);
    REDSTEP(acc0, 16) REDSTEP(acc1, 16) REDSTEP(acc2, 16) REDSTEP(acc3, 16)
    REDSTEP(acc0, 32) REDSTEP(acc1, 32) REDSTEP(acc2, 32) REDSTEP(acc3, 32)
#undef REDSTEP
    if ((tid & 48) == 0) {
        int ww = tid >> 6;
        zr[ww][bb +  0][4*cc+0] = acc0.x; zr[ww][bb +  0][4*cc+1] = acc0.y;
        zr[ww][bb +  0][4*cc+2] = acc0.z; zr[ww][bb +  0][4*cc+3] = acc0.w;
        zr[ww][bb +  4][4*cc+0] = acc1.x; zr[ww][bb +  4][4*cc+1] = acc1.y;
        zr[ww][bb +  4][4*cc+2] = acc1.z; zr[ww][bb +  4][4*cc+3] = acc1.w;
        zr[ww][bb +  8][4*cc+0] = acc2.x; zr[ww][bb +  8][4*cc+1] = acc2.y;
        zr[ww][bb +  8][4*cc+2] = acc2.z; zr[ww][bb +  8][4*cc+3] = acc2.w;
        zr[ww][bb + 12][4*cc+0] = acc3.x; zr[ww][bb + 12][4*cc+1] = acc3.y;
        zr[ww][bb + 12][4*cc+2] = acc3.z; zr[ww][bb + 12][4*cc+3] = acc3.w;
    }
    __syncthreads();
    if (tid < 256) {
        int b = tid >> 4, c = tid & 15;
        float z = bias[c0 + c];
        #pragma unroll
        for (int g = 0; g < 8; ++g) z += zr[g][b][c];
        hnext[(size_t)(b0 + b) * HH + c0 + c] = tanhf(z);
    }
}

__global__ __launch_bounds__(128)
void rnn_out(const float* __restrict__ h, const float* __restrict__ Wout,
             const float* __restrict__ bout, float* __restrict__ out)
{
    __shared__ float hl[HH];
    const int b = blockIdx.x, tid = threadIdx.x;
    for (int i = tid; i < HH / 4; i += 128)
        *reinterpret_cast<float4*>(hl + 4 * i) =
            *reinterpret_cast<const float4*>(h + (size_t)b * HH + 4 * i);
    __syncthreads();
    float a0 = bout[tid], a1 = 0.f, a2 = 0.f, a3 = 0.f;
    for (int j = 0; j < HH; j += 4) {
        a0 = fmaf(hl[j + 0], Wout[(size_t)(j + 0) * LL + tid], a0);
        a1 = fmaf(hl[j + 1], Wout[(size_t)(j + 1) * LL + tid], a1);
        a2 = fmaf(hl[j + 2], Wout[(size_t)(j + 2) * LL + tid], a2);
        a3 = fmaf(hl[j + 3], Wout[(size_t)(j + 3) * LL + tid], a3);
    }
    out[(size_t)b * LL + tid] = (a0 + a1) + (a2 + a3);
}

__global__ __launch_bounds__(512)
void rnn_scan_kernel(const float* __restrict__ x, const float* __restrict__ tf,
                     const float* __restrict__ W, const float* __restrict__ bias,
                     const float* __restrict__ Wout, const float* __restrict__ bout,
                     float* __restrict__ out)
{
    __shared__ float s[KD];
    const int b_idx = blockIdx.x, tid = threadIdx.x;
    if (tid < CIN)      s[tid] = x[b_idx * TT * CIN + tid];
    else if (tid < INF) s[tid] = tf[b_idx * TT * THF + (tid - CIN)];
    for (int i = tid; i < HH; i += 512) s[INF + i] = 0.0f;
    __syncthreads();
    const int j0 = tid * 2;
    const float bias0 = bias[j0], bias1 = bias[j0 + 1];
    for (int t = 0; t < TT; ++t) {
        float z0 = bias0, z1 = bias1;
        #pragma unroll 8
        for (int k = 0; k < KD; ++k) {
            const float2 wv = *reinterpret_cast<const float2*>(&W[(size_t)k * HH + j0]);
            const float sv = s[k];
            z0 = fmaf(sv, wv.x, z0);
            z1 = fmaf(sv, wv.y, z1);
        }
        float nin = 0.0f;
        const int tn = t + 1;
        if (tn < TT) {
            if (tid < CIN)      nin = x[b_idx * TT * CIN + tn * CIN + tid];
            else if (tid < INF) nin = tf[b_idx * TT * THF + tn * THF + (tid - CIN)];
        }
        __syncthreads();
        s[INF + j0]     = tanhf(z0);
        s[INF + j0 + 1] = tanhf(z1);
        if (tid < INF && tn < TT) s[tid] = nin;
        __syncthreads();
    }
    for (int lll = tid; lll < LL; lll += 512) {
        float acc = bout[lll];
        for (int j = 0; j < HH; ++j) acc = fmaf(s[INF + j], Wout[(size_t)j * LL + lll], acc);
        out[(size_t)b_idx * LL + lll] = acc;
    }
}

extern "C" void kernel_launch(void* const* d_in, const int* in_sizes, int n_in,
                              void* d_out, int out_size, void* d_ws, size_t ws_size,
                              hipStream_t stream) {
    const float* x    = (const float*)d_in[0];   // [64, 512, 32]
    const float* tf   = (const float*)d_in[1];   // [64, 512, 32]
    const float* W    = (const float*)d_in[2];   // [1088, 1024]
    const float* brnn = (const float*)d_in[3];   // [1024]
    const float* Wout = (const float*)d_in[4];   // [1024, 128]
    const float* bout = (const float*)d_in[5];   // [128]
    float* out = (float*)d_out;                  // [64, 1, 128]

    // ---- MFMA bf16 path ----
    const size_t hbf_bytes = 2ull * BB * HH * sizeof(unsigned short);
    const size_t wt_bytes  = (size_t)HH * KP * sizeof(unsigned short);
    if (ws_size >= hbf_bytes + wt_bytes) {
        unsigned short* hbf = (unsigned short*)d_ws;
        unsigned short* Wt  = hbf + 2ull * BB * HH;
        hipMemsetAsync(hbf, 0, (size_t)BB * HH * sizeof(unsigned short), stream);
        transposeW_bf16<<<dim3(HH / 32, KD / 32), dim3(32, 8), 0, stream>>>(W, Wt);
        for (int t = 0; t < TT; ++t) {
            rnn_step_mfma<<<256, 256, 0, stream>>>(x, tf, Wt, brnn,
                hbf + (size_t)(t & 1) * BB * HH,
                hbf + (size_t)((t + 1) & 1) * BB * HH, t);
        }
        rnn_out_bf16<<<BB, 128, 0, stream>>>(hbf /* parity 0 */, Wout, bout, out);
        return;
    }

    // ---- fp32 fallback (R7) ----
    float* hbuf = (float*)d_ws;
    const size_t hbuf_bytes = 2ull * BB * HH * sizeof(float);
    if (ws_size < hbuf_bytes) {
        rnn_scan_kernel<<<BB, 512, 0, stream>>>(x, tf, W, brnn, Wout, bout, out);
        return;
    }
    hipMemsetAsync(hbuf, 0, (size_t)BB * HH * sizeof(float), stream);
    for (int t = 0; t < TT; ++t) {
        rnn_step3<<<256, 512, 0, stream>>>(x, tf, W, brnn,
                                           hbuf + (size_t)(t & 1) * BB * HH,
                                           hbuf + (size_t)((t + 1) & 1) * BB * HH,
                                           t);
    }
    rnn_out<<<BB, 128, 0, stream>>>(hbuf, Wout, bout, out);
}